// Round 10
// baseline (271.731 us; speedup 1.0000x reference)
//
#include <hip/hip_runtime.h>
#include <hip/hip_cooperative_groups.h>
#include <math.h>

namespace cg = cooperative_groups;

#define BB 8
#define KK 20
#define CC 96
#define LOG2E 1.4426950408889634f

#define VB   512               // virtual blocks
#define THR  512
#define BPTS 256               // points per virtual block
#define CHK  64                // points per staged chunk
#define NCH  4                 // chunks per virtual block
#define FN   (CHK * CC)        // 6144 floats
#define PN   (CHK * KK)        // 1280 floats
#define BUFN (FN + PN)         // 7424 floats

// async global->LDS, 16B per lane, wave-uniform LDS base + lane*16
#define GLDS(g, l) __builtin_amdgcn_global_load_lds( \
    (const __attribute__((address_space(1))) void*)(g), \
    (__attribute__((address_space(3))) void*)(l), 16, 0, 0)

// stage chunk g of vb into buffer half h. per-wave vmem issue:
// waves 0-4: 3 feats + 1 probs = 4; waves 5-7: 3.
#define STAGE(g, h) {                                                       \
    const float* fsrc_ = feats + (size_t)(base + (g) * CHK) * CC;           \
    float* fb_ = buf + (h) * BUFN;                                          \
    _Pragma("unroll")                                                       \
    for (int i_ = 0; i_ < 3; ++i_)                                          \
      GLDS(fsrc_ + (size_t)(i_ * THR + t) * 4,                              \
           fb_ + (size_t)(i_ * THR + (t & ~63)) * 4);                       \
    const float* psrc_ = probs + (size_t)(base + (g) * CHK) * KK;           \
    if (t < 320)                                                            \
      GLDS(psrc_ + (size_t)t * 4, fb_ + FN + (size_t)(t & ~63) * 4);        \
  }

__launch_bounds__(THR, 4)
__global__ void fused_kernel(const float* __restrict__ feats,
                             const float* __restrict__ probs,
                             const int* __restrict__ bidx,
                             float* __restrict__ out,
                             float* __restrict__ sPartT,
                             float* __restrict__ part,
                             int useRed) {
  __shared__ __align__(16) float buf[2 * BUFN];   // 58 KB
  __shared__ float loff[BB * KK];                 // 640 B
  __shared__ float lacc[KK * CC];                 // 7.5 KB
  const int t = threadIdx.x;
  const int nb = gridDim.x;
  cg::grid_group gg = cg::this_grid();

  // ========== P1: per-vb exp2 sums -> sPartT[cell][VB] (transposed) =======
  if (blockIdx.x == 0)
    for (int i = t; i < BB * KK * CC; i += THR) out[i] = 0.f;
  float* ls = buf;                      // [64][160] scratch (40 KB <= 58 KB)
  for (int vb = blockIdx.x; vb < VB; vb += nb) {
    const int base = vb * BPTS;
    const int b0 = bidx[base];
    const bool multi = b0 != bidx[base + BPTS - 1];
    for (int i = t; i < 64 * BB * KK; i += THR) ls[i] = 0.f;
    __syncthreads();
    if (t < 320) {                      // no barriers inside
      const int p0 = (4 * t) / 20;      // 0..63
      const int k0 = (4 * t) % 20;      // granule stays within one point row
      const float4* src = (const float4*)(probs + (size_t)base * KK);
      float s0 = 0.f, s1 = 0.f, s2 = 0.f, s3 = 0.f;
      if (!multi) {
        #pragma unroll
        for (int i = 0; i < 4; ++i) {
          const float4 v = src[t + i * 320];
          s0 += exp2f(v.x * LOG2E); s1 += exp2f(v.y * LOG2E);
          s2 += exp2f(v.z * LOG2E); s3 += exp2f(v.w * LOG2E);
        }
        float* c = &ls[p0 * (BB * KK) + b0 * KK + k0];
        c[0] = s0; c[1] = s1; c[2] = s2; c[3] = s3;
      } else {
        int cb = bidx[base + p0];
        #pragma unroll
        for (int i = 0; i < 4; ++i) {
          const float4 v = src[t + i * 320];
          const int b = bidx[base + p0 + i * 64];
          if (b != cb) {                // sorted: each batch once per thread
            float* c = &ls[p0 * (BB * KK) + cb * KK + k0];
            c[0] = s0; c[1] = s1; c[2] = s2; c[3] = s3;
            s0 = s1 = s2 = s3 = 0.f; cb = b;
          }
          s0 += exp2f(v.x * LOG2E); s1 += exp2f(v.y * LOG2E);
          s2 += exp2f(v.z * LOG2E); s3 += exp2f(v.w * LOG2E);
        }
        float* c = &ls[p0 * (BB * KK) + cb * KK + k0];
        c[0] = s0; c[1] = s1; c[2] = s2; c[3] = s3;
      }
    }
    __syncthreads();
    if (t < BB * KK) {
      float S = 0.f;
      #pragma unroll
      for (int u = 0; u < 64; ++u) S += ls[u * (BB * KK) + t];  // bank-free
      sPartT[(size_t)t * VB + vb] = S;
    }
    __syncthreads();                    // before next iter re-zeroes ls
  }
  gg.sync();

  // ========== P2+P3 per vb: loff then pipelined gather ====================
  for (int vb = blockIdx.x; vb < VB; vb += nb) {
    const int base = vb * BPTS;
    const int b0 = bidx[base];
    const int bL = bidx[base + BPTS - 1];
    const bool multi = b0 != bL;
    // ---- P2: loff[bb][k] = log2(sum over all vb rows) for bb touched ----
    for (int bb = b0; bb <= bL; ++bb) {    // uniform loop, no barriers inside
      #pragma unroll
      for (int cq = 0; cq < 3; ++cq) {
        const int k = cq * 8 + (t >> 6);
        if (k < 20) {
          const float* sp = sPartT + (size_t)(bb * KK + k) * VB;
          float S = 0.f;
          #pragma unroll
          for (int i = 0; i < 8; ++i) S += sp[(t & 63) + i * 64];
          #pragma unroll
          for (int d = 1; d < 64; d <<= 1) S += __shfl_xor(S, d);
          if ((t & 63) == 0) loff[bb * KK + k] = (S > 0.f) ? log2f(S) : 3e38f;
        }
      }
    }
    for (int i = t; i < KK * CC; i += THR) lacc[i] = 0.f;

    const bool act = t < 480;
    const int pslot = t / 60, r = t % 60;
    const int kg = r / 12, cg = r % 12;
    int cb = b0;
    if (act && multi) cb = bidx[base + pslot * 8];
    asm volatile("s_waitcnt vmcnt(0)" ::: "memory");  // drain P2/cb loads
    __syncthreads();                                  // loff, lacc, buf free

    float offr[4];
    if (act) {
      #pragma unroll
      for (int i = 0; i < 4; ++i) offr[i] = loff[cb * KK + kg * 4 + i];
    }
    float acc[4][8];
    #pragma unroll
    for (int i = 0; i < 4; ++i)
      #pragma unroll
      for (int j = 0; j < 8; ++j) acc[i][j] = 0.f;

    STAGE(0, 0);
    for (int g = 0; g < NCH; ++g) {
      if (g + 1 < NCH) {
        STAGE(g + 1, (g + 1) & 1);
        asm volatile("s_waitcnt vmcnt(3)" ::: "memory");  // cur chunk landed
      } else {
        asm volatile("s_waitcnt vmcnt(0)" ::: "memory");
      }
      __builtin_amdgcn_s_barrier();
      __builtin_amdgcn_sched_barrier(0);

      const float* fb = buf + (g & 1) * BUFN;
      const float* pb = fb + FN;
      if (act) {
        const float* wp = pb + (pslot * 8) * KK + kg * 4;
        const float* f1 = fb + (size_t)(pslot * 8) * CC + cg * 4;
        const float* f2 = f1 + 48;
        #pragma unroll 4
        for (int pass = 0; pass < 8; ++pass) {
          if (multi) {
            const int b = bidx[base + g * CHK + pslot * 8 + pass];
            if (b != cb) {              // rare boundary: flush segment
              #pragma unroll
              for (int i = 0; i < 4; ++i)
                #pragma unroll
                for (int j = 0; j < 8; ++j) {
                  const int c = (j < 4) ? cg * 4 + j : 48 + cg * 4 + (j - 4);
                  atomicAdd(out + (size_t)cb * (KK * CC) + (kg * 4 + i) * CC + c,
                            acc[i][j]);
                  acc[i][j] = 0.f;
                }
              cb = b;
              #pragma unroll
              for (int i = 0; i < 4; ++i) offr[i] = loff[cb * KK + kg * 4 + i];
            }
          }
          const float4 w4 = *(const float4*)(wp + pass * KK);
          const float4 fA = *(const float4*)(f1 + (size_t)pass * CC);
          const float4 fB = *(const float4*)(f2 + (size_t)pass * CC);
          float wr[4];
          wr[0] = exp2f(fmaf(w4.x, LOG2E, -offr[0]));
          wr[1] = exp2f(fmaf(w4.y, LOG2E, -offr[1]));
          wr[2] = exp2f(fmaf(w4.z, LOG2E, -offr[2]));
          wr[3] = exp2f(fmaf(w4.w, LOG2E, -offr[3]));
          const float fr[8] = {fA.x, fA.y, fA.z, fA.w, fB.x, fB.y, fB.z, fB.w};
          #pragma unroll
          for (int i = 0; i < 4; ++i)
            #pragma unroll
            for (int j = 0; j < 8; ++j)
              acc[i][j] = fmaf(wr[i], fr[j], acc[i][j]);
        }
      }
      asm volatile("s_waitcnt lgkmcnt(0)" ::: "memory");  // LDS reads retired
      __builtin_amdgcn_s_barrier();
      __builtin_amdgcn_sched_barrier(0);
    }

    // ---- flush ----
    if (act) {
      if (multi) {
        #pragma unroll
        for (int i = 0; i < 4; ++i)
          #pragma unroll
          for (int j = 0; j < 8; ++j) {
            const int c = (j < 4) ? cg * 4 + j : 48 + cg * 4 + (j - 4);
            atomicAdd(out + (size_t)cb * (KK * CC) + (kg * 4 + i) * CC + c,
                      acc[i][j]);
          }
      } else {
        #pragma unroll
        for (int i = 0; i < 4; ++i)
          #pragma unroll
          for (int j = 0; j < 8; ++j) {
            const int c = (j < 4) ? cg * 4 + j : 48 + cg * 4 + (j - 4);
            atomicAdd(&lacc[(kg * 4 + i) * CC + c], acc[i][j]);
          }
      }
    }
    __syncthreads();
    if (!multi) {
      if (useRed) {
        for (int i = t; i < KK * CC; i += THR)
          part[(size_t)vb * (KK * CC) + i] = lacc[i];
      } else {
        for (int i = t; i < KK * CC; i += THR)
          atomicAdd(out + (size_t)b0 * (KK * CC) + i, lacc[i]);
      }
    }
    __syncthreads();                    // lacc/loff/buf reuse next vb
  }
  gg.sync();

  // ========== P4: reduce part -> out (64 slices) ==========================
  if (useRed) {
    for (int rb = blockIdx.x; rb < 64; rb += nb) {   // block-uniform count
      const int b = rb >> 3, cs = rb & 7;
      int* gb = (int*)lacc;
      {
        const int bA = bidx[t * BPTS];
        gb[t] = (bA == bidx[t * BPTS + BPTS - 1]) ? bA : -1;
      }
      __syncthreads();
      if (t < 240) {
        const int c = cs * 240 + t;
        float a = 0.f;
        for (int g = 0; g < VB; ++g)
          if (gb[g] == b)               // block-uniform branch
            a += part[(size_t)g * (KK * CC) + c];
        atomicAdd(out + (size_t)b * (KK * CC) + c, a);
      }
      __syncthreads();
    }
  }
}

extern "C" void kernel_launch(void* const* d_in, const int* in_sizes, int n_in,
                              void* d_out, int out_size, void* d_ws, size_t ws_size,
                              hipStream_t stream) {
  const float* feats = (const float*)d_in[0];
  const float* probs = (const float*)d_in[1];
  const int* bidx = (const int*)d_in[3];
  float* out = (float*)d_out;

  float* sPartT = (float*)d_ws;                        // [160][VB]
  float* part = sPartT + (size_t)BB * KK * VB;         // [VB][1920]
  const size_t need = ((size_t)BB * KK * VB +
                       (size_t)VB * KK * CC) * sizeof(float);
  int useRed = ws_size >= need;

  // deterministic host-side occupancy query (graph-safe, no alloc/sync)
  int occ = 1;
  (void)hipOccupancyMaxActiveBlocksPerMultiprocessor(&occ, fused_kernel, THR, 0);
  if (occ < 1) occ = 1;
  if (occ > 2) occ = 2;
  const int nb = 256 * occ;             // VB % nb == 0 for occ in {1,2}

  void* args[] = {(void*)&feats, (void*)&probs, (void*)&bidx,
                  (void*)&out, (void*)&sPartT, (void*)&part, (void*)&useRed};
  hipLaunchCooperativeKernel((const void*)fused_kernel, dim3(nb), dim3(THR),
                             args, 0, stream);
}